// Round 5
// baseline (113.822 us; speedup 1.0000x reference)
//
#include <hip/hip_runtime.h>
#include <math.h>

// monotonic_binary_output: out[r] = (u[r] < sigmoid-thresh[r]).
//
// v5: 4-deep global_load_lds pipeline (prefetch distance 3).
//  - 1 wave/block; 4 LDS buffers of 8-row chunks (8*129 floats = 4128 B,
//    16B-aligned for every chunk since 4128 % 16 == 0).
//  - stage = 6 DMA instrs (4 full-wave 1KB + 2-lane x-tail + 2-lane u).
//  - steady-state wait: s_waitcnt vmcnt(18) -- the 3 newer stages (18 instrs)
//    stay in flight; never drains to 0 inside the loop. Prologue: 24
//    outstanding -> <=18 drains exactly chunk 0's stage. Tail iters (no
//    stage issued) use vmcnt(0) (<=3 of ~61 iters/wave).
//  - latency coverage: distance-3 prefetch = ~3x compute (~1000 cy) >= HBM
//    ~900 cy, vs v4's distance-1 (~550 cy) which stalled every iteration.
//  - numerics unchanged: f32 hot path + rare f64 escape (re-reads x from
//    global); decisions identical to pure-f64 kernel (absmax 0.0, R1-R4).

constexpr int LATENT = 128;
constexpr int RS     = 129;          // x row stride in floats
constexpr int CH     = 8;            // rows per chunk
constexpr int CHF    = CH * RS;      // 1032 floats = 4128 B per chunk
constexpr int NBUF   = 4;            // pipeline depth
constexpr int CPL    = 8;            // cols per lane (16 lanes per row)
constexpr int ROWS   = 2;            // rows per 16-lane group

typedef float __attribute__((address_space(1))) gfloat;
typedef float __attribute__((address_space(3))) sfloat;

__device__ __forceinline__ void stage_chunk(const float* xg, const float* ug,
                                            float* lx, float* lu, int lane) {
    // 4 full wave-wide 1KB DMAs: floats [256k + 4*lane, +4)
#pragma unroll
    for (int k = 0; k < 4; ++k) {
        __builtin_amdgcn_global_load_lds((const gfloat*)(xg + 256 * k + 4 * lane),
                                         (sfloat*)(lx + 256 * k), 16, 0, 0);
    }
    // tails: floats 1024..1031 (2 lanes) and the 8-float u chunk (2 lanes)
    if (lane < 2) {
        __builtin_amdgcn_global_load_lds((const gfloat*)(xg + 1024 + 4 * lane),
                                         (sfloat*)(lx + 1024), 16, 0, 0);
        __builtin_amdgcn_global_load_lds((const gfloat*)(ug + 4 * lane),
                                         (sfloat*)lu, 16, 0, 0);
    }
}

__global__ __launch_bounds__(64, 1)
void mono_kernel(const float* __restrict__ x,
                 const float* __restrict__ W,
                 const float* __restrict__ b,
                 const float* __restrict__ u,
                 float* __restrict__ out,
                 int N)
{
    __shared__ __align__(16) float lx[NBUF][CHF];
    __shared__ __align__(16) float lu[NBUF][CH];

    const int lane = threadIdx.x;        // 0..63 (one wave per block)
    const int sub  = lane & 15;          // lane within 16-lane row-group
    const int gi   = lane >> 4;          // group 0..3 -> rows 2gi, 2gi+1
    const int w    = blockIdx.x;
    const int nw   = gridDim.x;
    const int NC   = N / CH;             // 125000 chunks

    // Lane's weight slice: cols c = sub + 16j (f32, exact copies of W).
    float w0f[CPL], w1f[CPL];
#pragma unroll
    for (int j = 0; j < CPL; ++j) {
        const int c = sub + 16 * j;
        w0f[j] = W[2 * c + 0];
        w1f[j] = W[2 * c + 1];
    }
    const float b0f = b[0], b1f = b[1];

    // Prologue: stage up to 3 chunks ahead.
#pragma unroll
    for (int k = 0; k < NBUF - 1; ++k) {
        const int c = w + k * nw;
        if (c < NC)
            stage_chunk(x + (size_t)c * CHF, u + (size_t)c * CH,
                        lx[k], lu[k], lane);
    }

    int it = 0;
    for (int c = w; c < NC; c += nw, ++it) {
        const int cur = it & (NBUF - 1);
        const int cn  = c + (NBUF - 1) * nw;      // chunk to stage now
        if (cn < NC) {
            stage_chunk(x + (size_t)cn * CHF, u + (size_t)cn * CH,
                        lx[(it + NBUF - 1) & (NBUF - 1)],
                        lu[(it + NBUF - 1) & (NBUF - 1)], lane);
            // 3 newer stages (18 instrs) may remain outstanding; chunk c's
            // stage is older than all of them -> guaranteed landed.
            asm volatile("s_waitcnt vmcnt(18)" ::: "memory");
        } else {
            asm volatile("s_waitcnt vmcnt(0)" ::: "memory");
        }

        const float* L  = lx[cur];
        const float* Lu = lu[cur];

        // ---- LDS -> regs (16 consecutive floats per group-instr) ----
        float fa[ROWS][CPL], zz[ROWS], uu[ROWS];
#pragma unroll
        for (int i = 0; i < ROWS; ++i) {
            const float* Lr = L + (ROWS * gi + i) * RS;
#pragma unroll
            for (int j = 0; j < CPL; ++j) fa[i][j] = Lr[sub + 16 * j];
            zz[i] = Lr[LATENT];
            uu[i] = Lu[ROWS * gi + i];
        }

        // ---- f32 dot: 4 independent FMA chains ----
        float s0[ROWS], s1[ROWS];
#pragma unroll
        for (int i = 0; i < ROWS; ++i) { s0[i] = 0.0f; s1[i] = 0.0f; }
#pragma unroll
        for (int j = 0; j < CPL; ++j) {
#pragma unroll
            for (int i = 0; i < ROWS; ++i) {
                s0[i] = fmaf(fa[i][j], w0f[j], s0[i]);
                s1[i] = fmaf(fa[i][j], w1f[j], s1[i]);
            }
        }

        // ---- butterfly reduce within 16-lane group ----
#pragma unroll
        for (int m = 8; m >= 1; m >>= 1) {
#pragma unroll
            for (int i = 0; i < ROWS; ++i) {
                s0[i] += __shfl_xor(s0[i], m, 64);
                s1[i] += __shfl_xor(s1[i], m, 64);
            }
        }

        // ---- f32 decision + conservative escalation ----
        float oo[ROWS];
        bool esc = false;
#pragma unroll
        for (int i = 0; i < ROWS; ++i) {
            const float l0 = s0[i] + b0f;
            const float l1 = s1[i] + b1f;
            const float t  = (zz[i] == 1.0f) ? fmaxf(l0, l1) : fminf(l0, l1);
            const float q  = uu[i] * (1.0f + expf(-t));
            oo[i] = (q < 1.0f) ? 1.0f : 0.0f;
            esc = esc || (fabsf(q - 1.0f) < 2.5e-4f * (1.0f + q));
        }

        // ---- rare exact f64 recompute (reloads x from global) ----
        if (__builtin_expect(esc, 0)) {
#pragma unroll 1
            for (int i = 0; i < ROWS; ++i) {
                const float* xr = x + (size_t)(c * CH + ROWS * gi + i) * RS;
                double d0 = 0.0, d1 = 0.0;
#pragma unroll
                for (int j = 0; j < CPL; ++j) {
                    const double xv = (double)xr[sub + 16 * j];
                    d0 = fma(xv, (double)w0f[j], d0);
                    d1 = fma(xv, (double)w1f[j], d1);
                }
#pragma unroll
                for (int m = 8; m >= 1; m >>= 1) {
                    d0 += __shfl_xor(d0, m, 64);
                    d1 += __shfl_xor(d1, m, 64);
                }
                const double l0 = d0 + (double)b0f;
                const double l1 = d1 + (double)b1f;
                const double t  = (zz[i] == 1.0f) ? fmax(l0, l1) : fmin(l0, l1);
                oo[i] = ((double)uu[i] * (1.0 + exp(-t)) < 1.0) ? 1.0f : 0.0f;
            }
        }

        if (sub == 0) {
            *reinterpret_cast<float2*>(out + c * CH + ROWS * gi) =
                make_float2(oo[0], oo[1]);
        }
    }
}

extern "C" void kernel_launch(void* const* d_in, const int* in_sizes, int n_in,
                              void* d_out, int out_size, void* d_ws, size_t ws_size,
                              hipStream_t stream) {
    const float* x = (const float*)d_in[0];
    const float* W = (const float*)d_in[1];
    const float* b = (const float*)d_in[2];
    const float* u = (const float*)d_in[3];
    float* out = (float*)d_out;
    const int N = in_sizes[3];   // u has N elements

    // 1 wave/block; LDS ~16.7 KB/block -> 8 blocks/CU at grid 2048 (256 CUs).
    mono_kernel<<<2048, 64, 0, stream>>>(x, W, b, u, out, N);
}

// Round 6
// 95.146 us; speedup vs baseline: 1.1963x; 1.1963x over previous
//
#include <hip/hip_runtime.h>
#include <math.h>

// monotonic_binary_output: out[r] = (u[r] < sigmoid-thresh[r]).
//
// v6 = v3 (best: 98.6 us) + forced 16B vector loads + grid 4096.
//  - Each lane reads two 16B row segments at 4B-aligned addresses (row
//    stride = 516 B). __builtin_memcpy forces a single dwordx4 per segment
//    (gfx950 unaligned-access-mode handles align-4 dwordx4), cutting VMEM
//    instructions ~3x per iteration if the compiler wasn't merging.
//  - numerics: f32 hot path + rare f64 escape (re-reads x from global),
//    decisions identical to the pure-f64 kernel (absmax == 0.0, R1-R5).

constexpr int LATENT = 128;
constexpr int RS     = 129;          // x row stride in floats
constexpr int LPR    = 16;           // lanes cooperating per row
constexpr int CPL    = 8;            // cols per lane
constexpr int ROWS   = 4;            // rows per group-iteration

__device__ __forceinline__ float4 load_f4(const float* p) {
    float4 v;
    __builtin_memcpy(&v, p, sizeof(float4));   // unaligned-safe 16B load
    return v;
}

__global__ __launch_bounds__(256, 2)
void mono_kernel(const float* __restrict__ x,
                 const float* __restrict__ W,
                 const float* __restrict__ b,
                 const float* __restrict__ u,
                 float* __restrict__ out,
                 int N)
{
    const int tid  = blockIdx.x * blockDim.x + threadIdx.x;
    const int sub  = threadIdx.x & (LPR - 1);
    const int grp  = tid >> 4;
    const int ngrp = (gridDim.x * blockDim.x) >> 4;

    // Lane's column set: c(j) = 4*sub + (j&3) + 64*(j>>2), j = 0..7.
    float w0f[CPL], w1f[CPL];
#pragma unroll
    for (int j = 0; j < CPL; ++j) {
        const int c = 4 * sub + (j & 3) + 64 * (j >> 2);
        w0f[j] = W[2 * c + 0];
        w1f[j] = W[2 * c + 1];
    }
    const float b0f = b[0];
    const float b1f = b[1];

    const int nquad = N >> 2;                    // N = 1e6, divisible by 4
    for (int g = grp; g < nquad; g += ngrp) {
        const int r0 = 4 * g;

        // ---- loads: two forced dwordx4 per row per lane + z + u ----
        float4 va[ROWS], vb[ROWS];
        float  zz[ROWS];
#pragma unroll
        for (int i = 0; i < ROWS; ++i) {
            const float* xr = x + (size_t)(r0 + i) * RS;
            va[i] = load_f4(xr + 4 * sub);          // floats [4s, 4s+3]
            vb[i] = load_f4(xr + 64 + 4 * sub);     // floats [64+4s, 64+4s+3]
            zz[i] = xr[LATENT];
        }
        const float4 uv = *reinterpret_cast<const float4*>(u + r0);
        const float uu[ROWS] = {uv.x, uv.y, uv.z, uv.w};

        // ---- f32 dot: 8 independent FMA chains ----
        float s0[ROWS], s1[ROWS];
#pragma unroll
        for (int i = 0; i < ROWS; ++i) {
            const float fa[CPL] = {va[i].x, va[i].y, va[i].z, va[i].w,
                                   vb[i].x, vb[i].y, vb[i].z, vb[i].w};
            float a0 = 0.0f, a1 = 0.0f;
#pragma unroll
            for (int j = 0; j < CPL; ++j) {
                a0 = fmaf(fa[j], w0f[j], a0);
                a1 = fmaf(fa[j], w1f[j], a1);
            }
            s0[i] = a0; s1[i] = a1;
        }

        // ---- butterfly reduce within the 16-lane group ----
#pragma unroll
        for (int m = 8; m >= 1; m >>= 1) {
#pragma unroll
            for (int i = 0; i < ROWS; ++i) {
                s0[i] += __shfl_xor(s0[i], m, 64);
                s1[i] += __shfl_xor(s1[i], m, 64);
            }
        }

        // ---- f32 decision with conservative escalation test ----
        float oo[ROWS];
        bool esc = false;
#pragma unroll
        for (int i = 0; i < ROWS; ++i) {
            const float l0 = s0[i] + b0f;
            const float l1 = s1[i] + b1f;
            const float t  = (zz[i] == 1.0f) ? fmaxf(l0, l1) : fminf(l0, l1);
            const float q  = uu[i] * (1.0f + expf(-t));
            oo[i] = (q < 1.0f) ? 1.0f : 0.0f;
            esc = esc || (fabsf(q - 1.0f) < 2.5e-4f * (1.0f + q));
        }

        // ---- rare exact f64 recompute (group-uniform branch; reloads x) ----
        if (__builtin_expect(esc, 0)) {
#pragma unroll 1
            for (int i = 0; i < ROWS; ++i) {
                const float* xr = x + (size_t)(r0 + i) * RS;
                double d0 = 0.0, d1 = 0.0;
#pragma unroll
                for (int j = 0; j < CPL; ++j) {
                    const int c = 4 * sub + (j & 3) + 64 * (j >> 2);
                    const double xv = (double)xr[c];
                    d0 = fma(xv, (double)w0f[j], d0);
                    d1 = fma(xv, (double)w1f[j], d1);
                }
#pragma unroll
                for (int m = 8; m >= 1; m >>= 1) {
                    d0 += __shfl_xor(d0, m, 64);
                    d1 += __shfl_xor(d1, m, 64);
                }
                const double l0 = d0 + (double)b0f;
                const double l1 = d1 + (double)b1f;
                const double t  = (zz[i] == 1.0f) ? fmax(l0, l1) : fmin(l0, l1);
                oo[i] = ((double)uu[i] * (1.0 + exp(-t)) < 1.0) ? 1.0f : 0.0f;
            }
        }

        if (sub == 0) {
            *reinterpret_cast<float4*>(out + r0) =
                make_float4(oo[0], oo[1], oo[2], oo[3]);
        }
    }
}

extern "C" void kernel_launch(void* const* d_in, const int* in_sizes, int n_in,
                              void* d_out, int out_size, void* d_ws, size_t ws_size,
                              hipStream_t stream) {
    const float* x = (const float*)d_in[0];
    const float* W = (const float*)d_in[1];
    const float* b = (const float*)d_in[2];
    const float* u = (const float*)d_in[3];
    float* out = (float*)d_out;
    const int N = in_sizes[3];   // u has N elements

    const int blocks = 4096;     // grid-stride; 256 thr = 16 groups/block
    mono_kernel<<<blocks, 256, 0, stream>>>(x, W, b, u, out, N);
}